// Round 1
// baseline (1799.683 us; speedup 1.0000x reference)
//
#include <hip/hip_runtime.h>
#include <cstddef>

// ---------------------------------------------------------------------------
// CapsNet forward, fp32 baseline.
// Pipeline:
//   1. k_transpose_w2 : prim_w (oc,ic,9,9) -> wT[k81][ic][oc]   (coalesced GEMM staging)
//   2. k_conv1        : x -> h (B,256,20,20), +bias, ReLU
//   3. k_conv2        : h -> p partials (K split in 2), implicit GEMM, fp32
//   4. k_squash1      : p halves + bias -> squash over 1152 -> U[b][i*8+k]
//   5. 3x routing iterations:
//        k_softmax -> k_wprime (fold c into W) -> k_gemm1 (split-K partial s_j)
//        -> k_redsq (reduce + class-axis squash) -> [k_gemm2 -> k_uv] (iters 0,1)
// ---------------------------------------------------------------------------

#define H_FLOATS   26214400   // 256*256*400
#define WT_FLOATS  5308416    // 81*256*256
#define PP_FLOATS  4718592    // 2 * 256*256*36
#define U_FLOATS   2359296    // 256*9216
#define PHALF      2359296

// overlays inside wT region (dead after conv2)
#define WP_OFF    0
#define PART_OFF  1474560
#define M2_OFF    2785280
#define CS_OFF    4259840
#define BIJ_OFF   4271360
#define OUTW_OFF  4282880

__global__ void k_transpose_w2(const float* __restrict__ w2, float* __restrict__ wT) {
    __shared__ float lds[64 * 82];
    int ic = blockIdx.x, ocg = blockIdx.y, t = threadIdx.x;
    for (int idx = t; idx < 5184; idx += 256) {
        int oc_l = idx / 81, kk = idx % 81;
        lds[oc_l * 82 + kk] = w2[((size_t)(ocg * 64 + oc_l) * 256 + ic) * 81 + kk];
    }
    __syncthreads();
    for (int idx = t; idx < 5184; idx += 256) {
        int kk = idx / 64, oc_l = idx % 64;
        wT[(size_t)kk * 65536 + ic * 256 + ocg * 64 + oc_l] = lds[oc_l * 82 + kk];
    }
}

__global__ void k_conv1(const float* __restrict__ x, const float* __restrict__ cw,
                        const float* __restrict__ cb, float* __restrict__ h) {
    // grid (256 b, 8 ocg), block 256
    __shared__ float img[784];
    __shared__ float wsm[32 * 81];
    int b = blockIdx.x, ocg = blockIdx.y, t = threadIdx.x;
    for (int idx = t; idx < 784; idx += 256) img[idx] = x[b * 784 + idx];
    for (int idx = t; idx < 2592; idx += 256) wsm[idx] = cw[ocg * 2592 + idx];
    __syncthreads();
    int oc_l = t & 31, g = t >> 5;
    int oc = ocg * 32 + oc_l;
    float bias = cb[oc];
    const float* wp = &wsm[oc_l * 81];
    for (int q = g; q < 100; q += 8) {
        int py = q / 5, qx = (q % 5) * 4;
        float a0 = bias, a1 = bias, a2 = bias, a3 = bias;
        #pragma unroll
        for (int ky = 0; ky < 9; ky++) {
            const float* ir = &img[(py + ky) * 28 + qx];
            float r[12];
            #pragma unroll
            for (int j = 0; j < 12; j++) r[j] = ir[j];
            #pragma unroll
            for (int kx = 0; kx < 9; kx++) {
                float w = wp[ky * 9 + kx];
                a0 += r[kx] * w; a1 += r[kx + 1] * w;
                a2 += r[kx + 2] * w; a3 += r[kx + 3] * w;
            }
        }
        float4 v = make_float4(fmaxf(a0, 0.f), fmaxf(a1, 0.f), fmaxf(a2, 0.f), fmaxf(a3, 0.f));
        *(float4*)&h[((size_t)b * 256 + oc) * 400 + py * 20 + qx] = v;
    }
}

__global__ __launch_bounds__(256, 2) void k_conv2(const float* __restrict__ h,
                                                  const float* __restrict__ wT,
                                                  float* __restrict__ pp) {
    // grid (64 bg, 4 ocg, 2 khalf), block 256. Tile: 4 batches x 64 oc, K-half=128 ic.
    __shared__ float sm[13568];    // hs[4][2][400]=3200 | wls[81][2][64]=10368 ; epilogue reuses sm[0..9216)
    float* hs = sm;
    float* wls = sm + 3200;
    int bg = blockIdx.x, ocg = blockIdx.y, kh = blockIdx.z, t = threadIdx.x;
    int tn = t & 15, tm = t >> 4;
    int off_r[9];
    #pragma unroll
    for (int rr = 0; rr < 9; rr++) {
        int m = tm * 9 + rr;
        int bl = m / 36, px = m % 36;
        int oy = px / 6, ox = px % 6;
        off_r[rr] = bl * 800 + oy * 40 + ox * 2;
    }
    float acc[9][4];
    #pragma unroll
    for (int rr = 0; rr < 9; rr++)
        #pragma unroll
        for (int q = 0; q < 4; q++) acc[rr][q] = 0.f;

    for (int ii = 0; ii < 64; ii++) {
        int icb = kh * 64 + ii;
        __syncthreads();
        for (int idx = t; idx < 800; idx += 256) {
            int blic = idx / 100, pos4 = idx % 100;
            int bl = blic >> 1, ic = blic & 1;
            *(float4*)&hs[blic * 400 + pos4 * 4] =
                *(const float4*)&h[(((size_t)(bg * 4 + bl)) * 256 + icb * 2 + ic) * 400 + pos4 * 4];
        }
        for (int idx = t; idx < 2592; idx += 256) {
            int kk = idx >> 5, r = idx & 31;
            int ic = r >> 4, v = r & 15;
            *(float4*)&wls[(kk * 2 + ic) * 64 + v * 4] =
                *(const float4*)&wT[((size_t)kk * 256 + icb * 2 + ic) * 256 + ocg * 64 + v * 4];
        }
        __syncthreads();
        for (int ky = 0; ky < 9; ky++) {
            #pragma unroll
            for (int kx = 0; kx < 9; kx++) {
                int kk = ky * 9 + kx;
                #pragma unroll
                for (int ic = 0; ic < 2; ic++) {
                    float4 wv = *(float4*)&wls[(kk * 2 + ic) * 64 + tn * 4];
                    #pragma unroll
                    for (int rr = 0; rr < 9; rr++) {
                        float a = hs[off_r[rr] + ic * 400 + ky * 20 + kx];
                        acc[rr][0] += a * wv.x;
                        acc[rr][1] += a * wv.y;
                        acc[rr][2] += a * wv.z;
                        acc[rr][3] += a * wv.w;
                    }
                }
            }
        }
    }
    __syncthreads();
    float* pl = sm;   // 9216 floats
    #pragma unroll
    for (int rr = 0; rr < 9; rr++) {
        int m = tm * 9 + rr;
        int bl = m / 36, px = m % 36;
        #pragma unroll
        for (int q = 0; q < 4; q++)
            pl[bl * 2304 + (tn * 4 + q) * 36 + px] = acc[rr][q];
    }
    __syncthreads();
    float* pout = pp + (size_t)kh * PHALF;
    for (int idx = t; idx < 2304; idx += 256) {
        int flat = idx * 4;
        int bl = flat / 2304, rem = flat % 2304;
        *(float4*)&pout[(((size_t)(bg * 4 + bl)) * 256 + ocg * 64) * 36 + rem] = *(float4*)&pl[flat];
    }
}

__global__ void k_squash1(const float* __restrict__ pp, const float* __restrict__ prim_b,
                          float* __restrict__ U) {
    // grid 2048 (b*8+cap), block 256
    __shared__ float red[4];
    int b = blockIdx.x >> 3, cap = blockIdx.x & 7;
    int t = threadIdx.x;
    const float* pa = pp + ((size_t)b * 256 + cap * 32) * 36;
    const float* pc = pa + PHALF;
    float v[5];
    float ss = 0.f;
    #pragma unroll
    for (int j = 0; j < 5; j++) {
        int idx = t + j * 256;
        if (idx < 1152) {
            int ch_l = idx / 36;
            float val = pa[idx] + pc[idx] + prim_b[cap * 32 + ch_l];
            v[j] = val; ss += val * val;
        } else v[j] = 0.f;
    }
    for (int off = 32; off; off >>= 1) ss += __shfl_down(ss, off);
    if ((t & 63) == 0) red[t >> 6] = ss;
    __syncthreads();
    float n2 = red[0] + red[1] + red[2] + red[3];
    float f = (n2 / (1.0f + n2)) / (sqrtf(n2) + 1e-10f);
    #pragma unroll
    for (int j = 0; j < 5; j++) {
        int idx = t + j * 256;
        if (idx < 1152) U[(size_t)b * 9216 + idx * 8 + cap] = v[j] * f;
    }
}

__global__ void k_softmax(const float* __restrict__ bij, float* __restrict__ csm) {
    // grid 10 (class), block 256; softmax over i=1152 (dim 0)
    __shared__ float red[4];
    int c = blockIdx.x, t = threadIdx.x;
    float vals[5];
    float mx = -1e30f;
    #pragma unroll
    for (int j = 0; j < 5; j++) {
        int i = t + j * 256;
        vals[j] = (i < 1152) ? bij[i * 10 + c] : -1e30f;
        mx = fmaxf(mx, vals[j]);
    }
    for (int off = 32; off; off >>= 1) mx = fmaxf(mx, __shfl_down(mx, off));
    if ((t & 63) == 0) red[t >> 6] = mx;
    __syncthreads();
    mx = fmaxf(fmaxf(red[0], red[1]), fmaxf(red[2], red[3]));
    __syncthreads();
    float s = 0.f;
    #pragma unroll
    for (int j = 0; j < 5; j++) {
        int i = t + j * 256;
        vals[j] = (i < 1152) ? expf(vals[j] - mx) : 0.f;
        s += vals[j];
    }
    for (int off = 32; off; off >>= 1) s += __shfl_down(s, off);
    if ((t & 63) == 0) red[t >> 6] = s;
    __syncthreads();
    s = red[0] + red[1] + red[2] + red[3];
    float inv = 1.0f / s;
    #pragma unroll
    for (int j = 0; j < 5; j++) {
        int i = t + j * 256;
        if (i < 1152) csm[i * 10 + c] = vals[j] * inv;
    }
}

__global__ void k_wprime(const float* __restrict__ dw, const float* __restrict__ csm,
                         float* __restrict__ wp) {
    // grid 1152 (i), block 256: wp[(i*8+k)*160 + c*16+o] = c[i,c]*W[i,c,o,k]
    __shared__ float lds[1280];
    __shared__ float cl[10];
    int i = blockIdx.x, t = threadIdx.x;
    for (int idx = t; idx < 1280; idx += 256) lds[idx] = dw[(size_t)i * 1280 + idx];
    if (t < 10) cl[t] = csm[i * 10 + t];
    __syncthreads();
    for (int idx = t; idx < 1280; idx += 256) {
        int k = idx / 160, co = idx % 160, c = co >> 4;
        wp[(size_t)i * 1280 + idx] = lds[co * 8 + k] * cl[c];
    }
}

__global__ __launch_bounds__(256) void k_gemm1(const float* __restrict__ U,
                                               const float* __restrict__ wp,
                                               float* __restrict__ part) {
    // grid (8 mb, 32 kc), block 256. partial[kc][b32][160] over K-chunk of 288.
    __shared__ float Us[32 * 36];
    __shared__ float Ws[32 * 160];
    int mb = blockIdx.x, kc = blockIdx.y, t = threadIdx.x;
    int tc = t & 15, tb = t >> 4;
    float acc[2][10] = {};
    for (int ks = 0; ks < 9; ks++) {
        __syncthreads();
        {
            int bb = t >> 3, k4 = t & 7;
            *(float4*)&Us[bb * 36 + k4 * 4] =
                *(const float4*)&U[(size_t)(mb * 32 + bb) * 9216 + kc * 288 + ks * 32 + k4 * 4];
        }
        for (int idx = t; idx < 1280; idx += 256) {
            int kk = idx / 40, c4 = idx % 40;
            *(float4*)&Ws[kk * 160 + c4 * 4] =
                *(const float4*)&wp[(size_t)(kc * 288 + ks * 32 + kk) * 160 + c4 * 4];
        }
        __syncthreads();
        for (int kk = 0; kk < 32; kk++) {
            float a0 = Us[(tb * 2) * 36 + kk], a1 = Us[(tb * 2 + 1) * 36 + kk];
            #pragma unroll
            for (int j = 0; j < 10; j++) {
                float w = Ws[kk * 160 + tc + 16 * j];
                acc[0][j] += a0 * w; acc[1][j] += a1 * w;
            }
        }
    }
    #pragma unroll
    for (int r = 0; r < 2; r++)
        #pragma unroll
        for (int j = 0; j < 10; j++)
            part[(size_t)kc * 40960 + (mb * 32 + tb * 2 + r) * 160 + tc + 16 * j] = acc[r][j];
}

__global__ void k_redsq(const float* __restrict__ part, float* __restrict__ out) {
    // grid 256 (b), block 256 (160 active): reduce 32 partials + squash over class axis
    __shared__ float sl[160];
    __shared__ float n2s[16];
    int b = blockIdx.x, t = threadIdx.x;
    float s = 0.f;
    if (t < 160) {
        for (int kc = 0; kc < 32; kc++) s += part[(size_t)kc * 40960 + b * 160 + t];
        sl[t] = s;
    }
    __syncthreads();
    if (t < 16) {
        float n2 = 0.f;
        #pragma unroll
        for (int c = 0; c < 10; c++) { float v = sl[c * 16 + t]; n2 += v * v; }
        n2s[t] = n2;
    }
    __syncthreads();
    if (t < 160) {
        float n2 = n2s[t & 15];
        float f = (n2 / (1.0f + n2)) / (sqrtf(n2) + 1e-10f);
        out[(size_t)b * 160 + t] = s * f;
    }
}

__global__ __launch_bounds__(256) void k_gemm2(const float* __restrict__ U,
                                               const float* __restrict__ outv,
                                               float* __restrict__ M2) {
    // grid 288 (m-blocks of 32), block 256. M2[ik][co] = sum_b U[b][ik]*outv[b][co]
    __shared__ float Us[32 * 36];
    __shared__ float Os[32 * 160];
    int blk = blockIdx.x, t = threadIdx.x;
    int tc = t & 15, tm = t >> 4;
    float acc[2][10] = {};
    for (int bs = 0; bs < 256; bs += 32) {
        __syncthreads();
        {
            int bb = t >> 3, m4 = t & 7;
            *(float4*)&Us[bb * 36 + m4 * 4] =
                *(const float4*)&U[(size_t)(bs + bb) * 9216 + blk * 32 + m4 * 4];
        }
        for (int idx = t; idx < 1280; idx += 256) {
            int bb = idx / 40, c4 = idx % 40;
            *(float4*)&Os[bb * 160 + c4 * 4] =
                *(const float4*)&outv[(size_t)(bs + bb) * 160 + c4 * 4];
        }
        __syncthreads();
        for (int bb = 0; bb < 32; bb++) {
            float a0 = Us[bb * 36 + tm * 2], a1 = Us[bb * 36 + tm * 2 + 1];
            #pragma unroll
            for (int j = 0; j < 10; j++) {
                float w = Os[bb * 160 + tc + 16 * j];
                acc[0][j] += a0 * w; acc[1][j] += a1 * w;
            }
        }
    }
    #pragma unroll
    for (int r = 0; r < 2; r++)
        #pragma unroll
        for (int j = 0; j < 10; j++)
            M2[(size_t)(blk * 32 + tm * 2 + r) * 160 + tc + 16 * j] = acc[r][j];
}

__global__ void k_uv(const float* __restrict__ dw, const float* __restrict__ M2,
                     float* __restrict__ bij) {
    // grid 1152 (i), block 256 (160 active): bij[i,c] += sum_{o,k} W[i,c,o,k]*M2[ik][co] / 256
    int i = blockIdx.x, t = threadIdx.x;
    if (t >= 160) return;
    int c = t >> 4, o = t & 15;
    (void)o;
    float4 w0 = *(const float4*)&dw[(size_t)i * 1280 + t * 8];
    float4 w1 = *(const float4*)&dw[(size_t)i * 1280 + t * 8 + 4];
    const float* wf0 = (const float*)&w0;
    const float* wf1 = (const float*)&w1;
    float v = 0.f;
    #pragma unroll
    for (int k = 0; k < 4; k++) v += wf0[k] * M2[(size_t)(i * 8 + k) * 160 + t];
    #pragma unroll
    for (int k = 0; k < 4; k++) v += wf1[k] * M2[(size_t)(i * 8 + 4 + k) * 160 + t];
    v += __shfl_down(v, 8, 16);
    v += __shfl_down(v, 4, 16);
    v += __shfl_down(v, 2, 16);
    v += __shfl_down(v, 1, 16);
    if ((t & 15) == 0) bij[i * 10 + c] += v * (1.0f / 256.0f);
}

extern "C" void kernel_launch(void* const* d_in, const int* in_sizes, int n_in,
                              void* d_out, int out_size, void* d_ws, size_t ws_size,
                              hipStream_t stream) {
    const float* x      = (const float*)d_in[0];
    const float* conv_w = (const float*)d_in[1];
    const float* conv_b = (const float*)d_in[2];
    const float* prim_w = (const float*)d_in[3];
    const float* prim_b = (const float*)d_in[4];
    const float* dw     = (const float*)d_in[5];

    float* ws   = (float*)d_ws;
    float* h    = ws;
    float* wT   = ws + H_FLOATS;
    float* pp   = ws + H_FLOATS + WT_FLOATS;
    float* U    = ws + H_FLOATS + WT_FLOATS + PP_FLOATS;
    // overlays in wT region (dead after conv2):
    float* wp   = wT + WP_OFF;
    float* part = wT + PART_OFF;
    float* M2   = wT + M2_OFF;
    float* csm  = wT + CS_OFF;
    float* bij  = wT + BIJ_OFF;
    float* outw = wT + OUTW_OFF;

    k_transpose_w2<<<dim3(256, 4), 256, 0, stream>>>(prim_w, wT);
    k_conv1<<<dim3(256, 8), 256, 0, stream>>>(x, conv_w, conv_b, h);
    k_conv2<<<dim3(64, 4, 2), 256, 0, stream>>>(h, wT, pp);
    k_squash1<<<2048, 256, 0, stream>>>(pp, prim_b, U);
    hipMemsetAsync(bij, 0, 11520 * sizeof(float), stream);

    for (int iter = 0; iter < 3; iter++) {
        k_softmax<<<10, 256, 0, stream>>>(bij, csm);
        k_wprime<<<1152, 256, 0, stream>>>(dw, csm, wp);
        k_gemm1<<<dim3(8, 32), 256, 0, stream>>>(U, wp, part);
        k_redsq<<<256, 256, 0, stream>>>(part, (iter == 2) ? (float*)d_out : outw);
        if (iter < 2) {
            k_gemm2<<<288, 256, 0, stream>>>(U, outw, M2);
            k_uv<<<1152, 256, 0, stream>>>(dw, M2, bij);
        }
    }
}

// Round 3
// 774.369 us; speedup vs baseline: 2.3241x; 2.3241x over previous
//
#include <hip/hip_runtime.h>
#include <cstdint>
#include <cstddef>

// ---------------------------------------------------------------------------
// CapsNet forward. Round 3: conv2 via split-bf16 MFMA (hh*wh + hh*wl + hl*wh).
// Round-2 bug fixed: each (ky,kx) now runs TWO 64-ic staging rounds (icb loop)
// so the full 128 ic per z-half are contracted (was silently dropping half K).
// ---------------------------------------------------------------------------

typedef __attribute__((ext_vector_type(8))) short short8;
typedef __attribute__((ext_vector_type(4))) float f32x4;

#define PHALF 2359296

#define WP_OFF    0
#define PART_OFF  1474560
#define M2_OFF    2785280
#define CS_OFF    4259840
#define BIJ_OFF   4271360
#define OUTW_OFF  4282880

__device__ __forceinline__ unsigned short f2bf_rn(float x) {
    unsigned u = __float_as_uint(x);
    unsigned r = (u + 0x7fffu + ((u >> 16) & 1u)) >> 16;
    return (unsigned short)r;
}
__device__ __forceinline__ float bf2f(unsigned short h) {
    return __uint_as_float(((unsigned)h) << 16);
}

// prim_w (256 oc, 256 ic, 81) fp32 -> wT_{hi,lo}[k][oc][ic] bf16
__global__ void k_makew(const float* __restrict__ w2,
                        unsigned short* __restrict__ wt_hi,
                        unsigned short* __restrict__ wt_lo) {
    __shared__ float lw[20736];   // [8 oc][32 ic][81 k]
    int ocg = blockIdx.x, icg = blockIdx.y, t = threadIdx.x;
    for (int idx = t; idx < 20736; idx += 256) {
        int row = idx / 81, k = idx % 81;
        int oc_l = row >> 5, ic_l = row & 31;
        lw[idx] = w2[((size_t)(ocg * 8 + oc_l) * 256 + icg * 32 + ic_l) * 81 + k];
    }
    __syncthreads();
    for (int idx = t; idx < 2592; idx += 256) {   // 81 k * 8 oc * 4 slots
        int k = idx >> 5;
        int r = idx & 31;
        int oc_l = r >> 2, sl = r & 3;
        unsigned short hi8[8], lo8[8];
        #pragma unroll
        for (int j = 0; j < 8; j++) {
            float v = lw[(oc_l * 32 + sl * 8 + j) * 81 + k];
            unsigned short h = f2bf_rn(v);
            hi8[j] = h;
            lo8[j] = f2bf_rn(v - bf2f(h));
        }
        size_t o = ((size_t)(k * 256 + ocg * 8 + oc_l)) * 256 + icg * 32 + sl * 8;
        *(uint4*)&wt_hi[o] = *(uint4*)hi8;
        *(uint4*)&wt_lo[o] = *(uint4*)lo8;
    }
}

__global__ void k_conv1(const float* __restrict__ x, const float* __restrict__ cw,
                        const float* __restrict__ cb,
                        unsigned short* __restrict__ h_hi,
                        unsigned short* __restrict__ h_lo) {
    // grid (256 b, 8 ocg), block 256
    __shared__ float img[784];
    __shared__ float wsm[32 * 81];
    int b = blockIdx.x, ocg = blockIdx.y, t = threadIdx.x;
    for (int idx = t; idx < 784; idx += 256) img[idx] = x[b * 784 + idx];
    for (int idx = t; idx < 2592; idx += 256) wsm[idx] = cw[ocg * 2592 + idx];
    __syncthreads();
    int oc_l = t & 31, g = t >> 5;
    int oc = ocg * 32 + oc_l;
    float bias = cb[oc];
    const float* wp = &wsm[oc_l * 81];
    for (int q = g; q < 100; q += 8) {
        int py = q / 5, qx = (q % 5) * 4;
        float a0 = bias, a1 = bias, a2 = bias, a3 = bias;
        #pragma unroll
        for (int ky = 0; ky < 9; ky++) {
            const float* ir = &img[(py + ky) * 28 + qx];
            float r[12];
            #pragma unroll
            for (int j = 0; j < 12; j++) r[j] = ir[j];
            #pragma unroll
            for (int kx = 0; kx < 9; kx++) {
                float w = wp[ky * 9 + kx];
                a0 += r[kx] * w; a1 += r[kx + 1] * w;
                a2 += r[kx + 2] * w; a3 += r[kx + 3] * w;
            }
        }
        float v[4] = { fmaxf(a0, 0.f), fmaxf(a1, 0.f), fmaxf(a2, 0.f), fmaxf(a3, 0.f) };
        size_t base = ((size_t)b * 400 + py * 20 + qx) * 256 + oc;
        #pragma unroll
        for (int j = 0; j < 4; j++) {
            unsigned short hh = f2bf_rn(v[j]);
            h_hi[base + (size_t)j * 256] = hh;
            h_lo[base + (size_t)j * 256] = f2bf_rn(v[j] - bf2f(hh));
        }
    }
}

// Implicit-GEMM MFMA conv2. grid (72 mb, 4 nb, 2 z), block 256 (4 waves).
// Block tile: 128 pixels x 64 oc, K = 81 kpos x 128 ic (per z), staged 64 ic/round.
__global__ __launch_bounds__(256) void k_conv2m(
    const unsigned short* __restrict__ h_hi, const unsigned short* __restrict__ h_lo,
    const unsigned short* __restrict__ wt_hi, const unsigned short* __restrict__ wt_lo,
    float* __restrict__ pp)
{
    // A_hi [0,8192) el | A_lo [8192,16384) | W_hi [16384,20480) | W_lo [20480,24576)
    __shared__ unsigned short smem[24576];   // 49152 B
    const int t = threadIdx.x;
    const int w = t >> 6, l = t & 63;
    const int mb = blockIdx.x, nb = blockIdx.y, z = blockIdx.z;
    const int ocb = nb * 64;

    // ---- staging setup: wave roles 0:A_hi 1:A_lo 2:W_hi 3:W_lo ----
    const unsigned short* src;
    int nld;
    unsigned rowbase[16];
    if (w < 2) {
        src = (w == 0) ? h_hi : h_lo;
        nld = 16;
        #pragma unroll
        for (int ld = 0; ld < 16; ld++) {
            int s = ld * 64 + l;
            int pix = s >> 3, ps = s & 7;
            int pg = ps ^ (pix & 7);
            int P = mb * 128 + pix;
            int b = P / 36, o = P % 36;
            int oy = o / 6, ox = o % 6;
            rowbase[ld] = (unsigned)((b * 400 + oy * 40 + ox * 2) * 256 + z * 128 + pg * 8);
        }
    } else {
        src = (w == 2) ? wt_hi : wt_lo;
        nld = 8;
        #pragma unroll
        for (int ld = 0; ld < 8; ld++) {
            int s = ld * 64 + l;
            int oc = s >> 3, ps = s & 7;
            int pg = ps ^ (oc & 7);
            rowbase[ld] = (unsigned)((ocb + oc) * 256 + z * 128 + pg * 8);
        }
    }
    const int sbase = (w < 2) ? w * 8192 : 16384 + (w - 2) * 4096;   // elements

    // ---- compute setup: waves 2x2, wave tile 64 pix x 32 oc ----
    const int wm = w & 1, wn = w >> 1;
    const int lane16 = l & 15, q = l >> 4;

    f32x4 acc[4][2] = {};

    for (int ky = 0; ky < 9; ky++) {
        for (int kx = 0; kx < 9; kx++) {
            for (int icb = 0; icb < 2; icb++) {
                const unsigned kofs = (w < 2)
                    ? (unsigned)((ky * 20 + kx) * 256 + icb * 64)
                    : (unsigned)((ky * 9 + kx) * 65536 + icb * 64);
                __syncthreads();
                for (int ld = 0; ld < nld; ld++) {
                    __builtin_amdgcn_global_load_lds(
                        (const __attribute__((address_space(1))) unsigned int*)(const void*)(src + rowbase[ld] + kofs),
                        (__attribute__((address_space(3))) unsigned int*)(void*)(smem + sbase + ld * 512),
                        16, 0, 0);
                }
                __syncthreads();
                #pragma unroll
                for (int icc = 0; icc < 2; icc++) {
                    short8 ah[4], al[4], bh[2], bl[2];
                    #pragma unroll
                    for (int mt = 0; mt < 4; mt++) {
                        int pixL = wm * 64 + mt * 16 + lane16;
                        int ps = (icc * 4 + q) ^ (pixL & 7);
                        const unsigned short* ap = smem + pixL * 64 + ps * 8;
                        ah[mt] = *(const short8*)ap;
                        al[mt] = *(const short8*)(ap + 8192);
                    }
                    #pragma unroll
                    for (int nt = 0; nt < 2; nt++) {
                        int ocL = wn * 32 + nt * 16 + lane16;
                        int ps = (icc * 4 + q) ^ (ocL & 7);
                        const unsigned short* bp = smem + 16384 + ocL * 64 + ps * 8;
                        bh[nt] = *(const short8*)bp;
                        bl[nt] = *(const short8*)(bp + 4096);
                    }
                    #pragma unroll
                    for (int mt = 0; mt < 4; mt++) {
                        #pragma unroll
                        for (int nt = 0; nt < 2; nt++) {
                            acc[mt][nt] = __builtin_amdgcn_mfma_f32_16x16x32_bf16(ah[mt], bh[nt], acc[mt][nt], 0, 0, 0);
                            acc[mt][nt] = __builtin_amdgcn_mfma_f32_16x16x32_bf16(ah[mt], bl[nt], acc[mt][nt], 0, 0, 0);
                            acc[mt][nt] = __builtin_amdgcn_mfma_f32_16x16x32_bf16(al[mt], bh[nt], acc[mt][nt], 0, 0, 0);
                        }
                    }
                }
            }
        }
    }

    // ---- epilogue: D row = quad*4+reg (pixel), col = lane16 (oc) ----
    float* pout = pp + (size_t)z * PHALF;
    #pragma unroll
    for (int mt = 0; mt < 4; mt++) {
        int pixG = mb * 128 + wm * 64 + mt * 16 + q * 4;
        int b = pixG / 36, p36 = pixG % 36;
        #pragma unroll
        for (int nt = 0; nt < 2; nt++) {
            int oc = ocb + wn * 32 + nt * 16 + lane16;
            f32x4 v = acc[mt][nt];
            *(f32x4*)&pout[((size_t)(b * 256 + oc)) * 36 + p36] = v;
        }
    }
}

__global__ void k_squash1(const float* __restrict__ pp, const float* __restrict__ prim_b,
                          float* __restrict__ U) {
    // grid 2048 (b*8+cap), block 256
    __shared__ float red[4];
    int b = blockIdx.x >> 3, cap = blockIdx.x & 7;
    int t = threadIdx.x;
    const float* pa = pp + ((size_t)b * 256 + cap * 32) * 36;
    const float* pc = pa + PHALF;
    float v[5];
    float ss = 0.f;
    #pragma unroll
    for (int j = 0; j < 5; j++) {
        int idx = t + j * 256;
        if (idx < 1152) {
            int ch_l = idx / 36;
            float val = pa[idx] + pc[idx] + prim_b[cap * 32 + ch_l];
            v[j] = val; ss += val * val;
        } else v[j] = 0.f;
    }
    for (int off = 32; off; off >>= 1) ss += __shfl_down(ss, off);
    if ((t & 63) == 0) red[t >> 6] = ss;
    __syncthreads();
    float n2 = red[0] + red[1] + red[2] + red[3];
    float f = (n2 / (1.0f + n2)) / (sqrtf(n2) + 1e-10f);
    #pragma unroll
    for (int j = 0; j < 5; j++) {
        int idx = t + j * 256;
        if (idx < 1152) U[(size_t)b * 9216 + idx * 8 + cap] = v[j] * f;
    }
}

__global__ void k_softmax(const float* __restrict__ bij, float* __restrict__ csm) {
    __shared__ float red[4];
    int c = blockIdx.x, t = threadIdx.x;
    float vals[5];
    float mx = -1e30f;
    #pragma unroll
    for (int j = 0; j < 5; j++) {
        int i = t + j * 256;
        vals[j] = (i < 1152) ? bij[i * 10 + c] : -1e30f;
        mx = fmaxf(mx, vals[j]);
    }
    for (int off = 32; off; off >>= 1) mx = fmaxf(mx, __shfl_down(mx, off));
    if ((t & 63) == 0) red[t >> 6] = mx;
    __syncthreads();
    mx = fmaxf(fmaxf(red[0], red[1]), fmaxf(red[2], red[3]));
    __syncthreads();
    float s = 0.f;
    #pragma unroll
    for (int j = 0; j < 5; j++) {
        int i = t + j * 256;
        vals[j] = (i < 1152) ? expf(vals[j] - mx) : 0.f;
        s += vals[j];
    }
    for (int off = 32; off; off >>= 1) s += __shfl_down(s, off);
    if ((t & 63) == 0) red[t >> 6] = s;
    __syncthreads();
    s = red[0] + red[1] + red[2] + red[3];
    float inv = 1.0f / s;
    #pragma unroll
    for (int j = 0; j < 5; j++) {
        int i = t + j * 256;
        if (i < 1152) csm[i * 10 + c] = vals[j] * inv;
    }
}

__global__ void k_wprime(const float* __restrict__ dw, const float* __restrict__ csm,
                         float* __restrict__ wp) {
    __shared__ float lds[1280];
    __shared__ float cl[10];
    int i = blockIdx.x, t = threadIdx.x;
    for (int idx = t; idx < 1280; idx += 256) lds[idx] = dw[(size_t)i * 1280 + idx];
    if (t < 10) cl[t] = csm[i * 10 + t];
    __syncthreads();
    for (int idx = t; idx < 1280; idx += 256) {
        int k = idx / 160, co = idx % 160, c = co >> 4;
        wp[(size_t)i * 1280 + idx] = lds[co * 8 + k] * cl[c];
    }
}

__global__ __launch_bounds__(256) void k_gemm1(const float* __restrict__ U,
                                               const float* __restrict__ wp,
                                               float* __restrict__ part) {
    __shared__ float Us[32 * 36];
    __shared__ float Ws[32 * 160];
    int mb = blockIdx.x, kc = blockIdx.y, t = threadIdx.x;
    int tc = t & 15, tb = t >> 4;
    float acc[2][10] = {};
    for (int ks = 0; ks < 9; ks++) {
        __syncthreads();
        {
            int bb = t >> 3, k4 = t & 7;
            *(float4*)&Us[bb * 36 + k4 * 4] =
                *(const float4*)&U[(size_t)(mb * 32 + bb) * 9216 + kc * 288 + ks * 32 + k4 * 4];
        }
        for (int idx = t; idx < 1280; idx += 256) {
            int kk = idx / 40, c4 = idx % 40;
            *(float4*)&Ws[kk * 160 + c4 * 4] =
                *(const float4*)&wp[(size_t)(kc * 288 + ks * 32 + kk) * 160 + c4 * 4];
        }
        __syncthreads();
        for (int kk = 0; kk < 32; kk++) {
            float a0 = Us[(tb * 2) * 36 + kk], a1 = Us[(tb * 2 + 1) * 36 + kk];
            #pragma unroll
            for (int j = 0; j < 10; j++) {
                float w = Ws[kk * 160 + tc + 16 * j];
                acc[0][j] += a0 * w; acc[1][j] += a1 * w;
            }
        }
    }
    #pragma unroll
    for (int r = 0; r < 2; r++)
        #pragma unroll
        for (int j = 0; j < 10; j++)
            part[(size_t)kc * 40960 + (mb * 32 + tb * 2 + r) * 160 + tc + 16 * j] = acc[r][j];
}

__global__ void k_redsq(const float* __restrict__ part, float* __restrict__ out) {
    __shared__ float sl[160];
    __shared__ float n2s[16];
    int b = blockIdx.x, t = threadIdx.x;
    float s = 0.f;
    if (t < 160) {
        for (int kc = 0; kc < 32; kc++) s += part[(size_t)kc * 40960 + b * 160 + t];
        sl[t] = s;
    }
    __syncthreads();
    if (t < 16) {
        float n2 = 0.f;
        #pragma unroll
        for (int c = 0; c < 10; c++) { float v = sl[c * 16 + t]; n2 += v * v; }
        n2s[t] = n2;
    }
    __syncthreads();
    if (t < 160) {
        float n2 = n2s[t & 15];
        float f = (n2 / (1.0f + n2)) / (sqrtf(n2) + 1e-10f);
        out[(size_t)b * 160 + t] = s * f;
    }
}

__global__ __launch_bounds__(256) void k_gemm2(const float* __restrict__ U,
                                               const float* __restrict__ outv,
                                               float* __restrict__ M2) {
    __shared__ float Us[32 * 36];
    __shared__ float Os[32 * 160];
    int blk = blockIdx.x, t = threadIdx.x;
    int tc = t & 15, tm = t >> 4;
    float acc[2][10] = {};
    for (int bs = 0; bs < 256; bs += 32) {
        __syncthreads();
        {
            int bb = t >> 3, m4 = t & 7;
            *(float4*)&Us[bb * 36 + m4 * 4] =
                *(const float4*)&U[(size_t)(bs + bb) * 9216 + blk * 32 + m4 * 4];
        }
        for (int idx = t; idx < 1280; idx += 256) {
            int bb = idx / 40, c4 = idx % 40;
            *(float4*)&Os[bb * 160 + c4 * 4] =
                *(const float4*)&outv[(size_t)(bs + bb) * 160 + c4 * 4];
        }
        __syncthreads();
        for (int bb = 0; bb < 32; bb++) {
            float a0 = Us[bb * 36 + tm * 2], a1 = Us[bb * 36 + tm * 2 + 1];
            #pragma unroll
            for (int j = 0; j < 10; j++) {
                float w = Os[bb * 160 + tc + 16 * j];
                acc[0][j] += a0 * w; acc[1][j] += a1 * w;
            }
        }
    }
    #pragma unroll
    for (int r = 0; r < 2; r++)
        #pragma unroll
        for (int j = 0; j < 10; j++)
            M2[(size_t)(blk * 32 + tm * 2 + r) * 160 + tc + 16 * j] = acc[r][j];
}

__global__ void k_uv(const float* __restrict__ dw, const float* __restrict__ M2,
                     float* __restrict__ bij) {
    int i = blockIdx.x, t = threadIdx.x;
    if (t >= 160) return;
    int c = t >> 4;
    float4 w0 = *(const float4*)&dw[(size_t)i * 1280 + t * 8];
    float4 w1 = *(const float4*)&dw[(size_t)i * 1280 + t * 8 + 4];
    const float* wf0 = (const float*)&w0;
    const float* wf1 = (const float*)&w1;
    float v = 0.f;
    #pragma unroll
    for (int k = 0; k < 4; k++) v += wf0[k] * M2[(size_t)(i * 8 + k) * 160 + t];
    #pragma unroll
    for (int k = 0; k < 4; k++) v += wf1[k] * M2[(size_t)(i * 8 + 4 + k) * 160 + t];
    v += __shfl_down(v, 8, 16);
    v += __shfl_down(v, 4, 16);
    v += __shfl_down(v, 2, 16);
    v += __shfl_down(v, 1, 16);
    if ((t & 15) == 0) bij[i * 10 + c] += v * (1.0f / 256.0f);
}

extern "C" void kernel_launch(void* const* d_in, const int* in_sizes, int n_in,
                              void* d_out, int out_size, void* d_ws, size_t ws_size,
                              hipStream_t stream) {
    const float* x      = (const float*)d_in[0];
    const float* conv_w = (const float*)d_in[1];
    const float* conv_b = (const float*)d_in[2];
    const float* prim_w = (const float*)d_in[3];
    const float* prim_b = (const float*)d_in[4];
    const float* dw     = (const float*)d_in[5];

    char* wsb = (char*)d_ws;
    unsigned short* h_hi  = (unsigned short*)(wsb);
    unsigned short* h_lo  = (unsigned short*)(wsb + 52428800);
    unsigned short* wt_hi = (unsigned short*)(wsb + 104857600);
    unsigned short* wt_lo = (unsigned short*)(wsb + 115474432);
    float* pp = (float*)(wsb + 126091264);
    float* U  = (float*)(wsb + 144965632);

    // routing overlays in h region (dead after conv2m/squash1)
    float* rb   = (float*)wsb;
    float* wp   = rb + WP_OFF;
    float* part = rb + PART_OFF;
    float* M2   = rb + M2_OFF;
    float* csm  = rb + CS_OFF;
    float* bij  = rb + BIJ_OFF;
    float* outw = rb + OUTW_OFF;

    k_makew<<<dim3(32, 8), 256, 0, stream>>>(prim_w, wt_hi, wt_lo);
    k_conv1<<<dim3(256, 8), 256, 0, stream>>>(x, conv_w, conv_b, h_hi, h_lo);
    k_conv2m<<<dim3(72, 4, 2), 256, 0, stream>>>(h_hi, h_lo, wt_hi, wt_lo, pp);
    k_squash1<<<2048, 256, 0, stream>>>(pp, prim_b, U);
    hipMemsetAsync(bij, 0, 11520 * sizeof(float), stream);

    for (int iter = 0; iter < 3; iter++) {
        k_softmax<<<10, 256, 0, stream>>>(bij, csm);
        k_wprime<<<1152, 256, 0, stream>>>(dw, csm, wp);
        k_gemm1<<<dim3(8, 32), 256, 0, stream>>>(U, wp, part);
        k_redsq<<<256, 256, 0, stream>>>(part, (iter == 2) ? (float*)d_out : outw);
        if (iter < 2) {
            k_gemm2<<<288, 256, 0, stream>>>(U, outw, M2);
            k_uv<<<1152, 256, 0, stream>>>(dw, M2, bij);
        }
    }
}

// Round 4
// 604.200 us; speedup vs baseline: 2.9786x; 1.2816x over previous
//
#include <hip/hip_runtime.h>
#include <cstdint>
#include <cstddef>

// ---------------------------------------------------------------------------
// CapsNet forward. Round 4:
//  - conv2 in pure bf16 MFMA (1 term; error budget 2% rel, this costs ~0.16%)
//  - 128-ic staging rounds (81 rounds, half the barriers of round 3)
//  - k_wprime eliminated (dwT precomputed once; c_ij folded into gemm1 staging)
//  - gemm2+uv fused into k_g2uv (M2 buffer gone)
// Workspace layout (bytes):
//   h    [0, 52428800)          bf16 [b][pix400][ic256]
//   wt   [52428800, 63045632)   bf16 [k81][oc256][ic256]
//   pp   [63045632, 81920000)   f32  2 z-halves of [b][oc][36]
//   U    [81920000, 91357184)   f32  [b][i*8+cap]
//   dwT  [91357184, 97255424)   f32  [ik9216][co160]
//   part [97255424, 102498304)  f32  [kc32][b256][co160]
//   csm  [102498304,102544384)  f32  [i][c]
//   bij  [102544384,102590464)  f32  [i][c]
//   outw [102590464,102754304)  f32  [b][co160]
// ---------------------------------------------------------------------------

typedef __attribute__((ext_vector_type(8))) short short8;
typedef __attribute__((ext_vector_type(4))) float f32x4;

#define PHALF 2359296

__device__ __forceinline__ unsigned short f2bf_rn(float x) {
    unsigned u = __float_as_uint(x);
    unsigned r = (u + 0x7fffu + ((u >> 16) & 1u)) >> 16;
    return (unsigned short)r;
}

// prim_w (256 oc, 256 ic, 81) fp32 -> wt[k][oc][ic] bf16
__global__ void k_makew(const float* __restrict__ w2,
                        unsigned short* __restrict__ wt) {
    __shared__ float lw[20736];   // [8 oc][32 ic][81 k]
    int ocg = blockIdx.x, icg = blockIdx.y, t = threadIdx.x;
    for (int idx = t; idx < 20736; idx += 256) {
        int row = idx / 81, k = idx % 81;
        int oc_l = row >> 5, ic_l = row & 31;
        lw[idx] = w2[((size_t)(ocg * 8 + oc_l) * 256 + icg * 32 + ic_l) * 81 + k];
    }
    __syncthreads();
    for (int idx = t; idx < 2592; idx += 256) {   // 81 k * 8 oc * 4 slots
        int k = idx >> 5;
        int r = idx & 31;
        int oc_l = r >> 2, sl = r & 3;
        unsigned short hi8[8];
        #pragma unroll
        for (int j = 0; j < 8; j++)
            hi8[j] = f2bf_rn(lw[(oc_l * 32 + sl * 8 + j) * 81 + k]);
        size_t o = ((size_t)(k * 256 + ocg * 8 + oc_l)) * 256 + icg * 32 + sl * 8;
        *(uint4*)&wt[o] = *(uint4*)hi8;
    }
}

__global__ void k_conv1(const float* __restrict__ x, const float* __restrict__ cw,
                        const float* __restrict__ cb,
                        unsigned short* __restrict__ h) {
    // grid (256 b, 8 ocg), block 256
    __shared__ float img[784];
    __shared__ float wsm[32 * 81];
    int b = blockIdx.x, ocg = blockIdx.y, t = threadIdx.x;
    for (int idx = t; idx < 784; idx += 256) img[idx] = x[b * 784 + idx];
    for (int idx = t; idx < 2592; idx += 256) wsm[idx] = cw[ocg * 2592 + idx];
    __syncthreads();
    int oc_l = t & 31, g = t >> 5;
    int oc = ocg * 32 + oc_l;
    float bias = cb[oc];
    const float* wp = &wsm[oc_l * 81];
    for (int q = g; q < 100; q += 8) {
        int py = q / 5, qx = (q % 5) * 4;
        float a0 = bias, a1 = bias, a2 = bias, a3 = bias;
        #pragma unroll
        for (int ky = 0; ky < 9; ky++) {
            const float* ir = &img[(py + ky) * 28 + qx];
            float r[12];
            #pragma unroll
            for (int j = 0; j < 12; j++) r[j] = ir[j];
            #pragma unroll
            for (int kx = 0; kx < 9; kx++) {
                float w = wp[ky * 9 + kx];
                a0 += r[kx] * w; a1 += r[kx + 1] * w;
                a2 += r[kx + 2] * w; a3 += r[kx + 3] * w;
            }
        }
        float v[4] = { fmaxf(a0, 0.f), fmaxf(a1, 0.f), fmaxf(a2, 0.f), fmaxf(a3, 0.f) };
        size_t base = ((size_t)b * 400 + py * 20 + qx) * 256 + oc;
        #pragma unroll
        for (int j = 0; j < 4; j++)
            h[base + (size_t)j * 256] = f2bf_rn(v[j]);
    }
}

// Implicit-GEMM bf16 MFMA conv2. grid (72 mb, 4 nb, 2 z), block 256 (4 waves).
// Tile: 128 pix x 64 oc; per round stage full 128 ic (one kernel position).
__global__ __launch_bounds__(256) void k_conv2m(
    const unsigned short* __restrict__ h,
    const unsigned short* __restrict__ wt,
    float* __restrict__ pp)
{
    // A [0,16384) el (128pix x 128ic) | W [16384,24576) el (64oc x 128ic)
    __shared__ unsigned short smem[24576];   // 49152 B
    const int t = threadIdx.x;
    const int w = t >> 6, l = t & 63;
    const int mb = blockIdx.x, nb = blockIdx.y, z = blockIdx.z;

    // ---- staging setup: w0 A pix 0-63, w1 A pix 64-127, w2 W oc 0-31, w3 W oc 32-63
    const unsigned short* src;
    int nld;
    unsigned rowbase[16];
    if (w < 2) {
        src = h;
        nld = 16;
        #pragma unroll
        for (int ld = 0; ld < 16; ld++) {
            int p_local = w * 64 + ld * 4 + (l >> 4);     // 0..127
            int c = l & 15;
            int g = c ^ (p_local & 7);
            int P = mb * 128 + p_local;
            int b = P / 36, o = P % 36;
            int oy = o / 6, ox = o % 6;
            rowbase[ld] = (unsigned)((b * 400 + oy * 40 + ox * 2) * 256 + z * 128 + g * 8);
        }
    } else {
        src = wt;
        nld = 8;
        #pragma unroll
        for (int ld = 0; ld < 8; ld++) {
            int oc_l = (w - 2) * 32 + ld * 4 + (l >> 4);  // 0..63
            int c = l & 15;
            int g = c ^ (oc_l & 7);
            rowbase[ld] = (unsigned)((nb * 64 + oc_l) * 256 + z * 128 + g * 8);
        }
    }
    const int sbase = (w < 2) ? w * 8192 : 16384 + (w - 2) * 4096;   // elements

    // ---- compute setup: waves 2x2, wave tile 64 pix x 32 oc ----
    const int wm = w & 1, wn = w >> 1;
    const int lane16 = l & 15, q = l >> 4;

    f32x4 acc[4][2] = {};

    for (int ky = 0; ky < 9; ky++) {
        for (int kx = 0; kx < 9; kx++) {
            const unsigned kofs = (w < 2) ? (unsigned)((ky * 20 + kx) * 256)
                                          : (unsigned)((ky * 9 + kx) * 65536);
            __syncthreads();
            for (int ld = 0; ld < nld; ld++) {
                __builtin_amdgcn_global_load_lds(
                    (const __attribute__((address_space(1))) unsigned int*)(const void*)(src + rowbase[ld] + kofs),
                    (__attribute__((address_space(3))) unsigned int*)(void*)(smem + sbase + ld * 512),
                    16, 0, 0);
            }
            __syncthreads();
            #pragma unroll
            for (int icc = 0; icc < 4; icc++) {
                short8 a[4], b[2];
                #pragma unroll
                for (int mt = 0; mt < 4; mt++) {
                    int pixL = wm * 64 + mt * 16 + lane16;
                    int s = (icc * 4 + q) ^ (pixL & 7);
                    a[mt] = *(const short8*)(smem + pixL * 128 + s * 8);
                }
                #pragma unroll
                for (int nt = 0; nt < 2; nt++) {
                    int ocL = wn * 32 + nt * 16 + lane16;
                    int s = (icc * 4 + q) ^ (ocL & 7);
                    b[nt] = *(const short8*)(smem + 16384 + ocL * 128 + s * 8);
                }
                #pragma unroll
                for (int mt = 0; mt < 4; mt++)
                    #pragma unroll
                    for (int nt = 0; nt < 2; nt++)
                        acc[mt][nt] = __builtin_amdgcn_mfma_f32_16x16x32_bf16(a[mt], b[nt], acc[mt][nt], 0, 0, 0);
            }
        }
    }

    // ---- epilogue: D row = q*4+reg (pixel), col = lane16 (oc) ----
    float* pout = pp + (size_t)z * PHALF;
    #pragma unroll
    for (int mt = 0; mt < 4; mt++) {
        int pixG = mb * 128 + wm * 64 + mt * 16 + q * 4;
        int b = pixG / 36, p36 = pixG % 36;
        #pragma unroll
        for (int nt = 0; nt < 2; nt++) {
            int oc = nb * 64 + wn * 32 + nt * 16 + lane16;
            f32x4 v = acc[mt][nt];
            *(f32x4*)&pout[((size_t)(b * 256 + oc)) * 36 + p36] = v;
        }
    }
}

__global__ void k_squash1(const float* __restrict__ pp, const float* __restrict__ prim_b,
                          float* __restrict__ U) {
    // grid 2048 (b*8+cap), block 256
    __shared__ float red[4];
    int b = blockIdx.x >> 3, cap = blockIdx.x & 7;
    int t = threadIdx.x;
    const float* pa = pp + ((size_t)b * 256 + cap * 32) * 36;
    const float* pc = pa + PHALF;
    float v[5];
    float ss = 0.f;
    #pragma unroll
    for (int j = 0; j < 5; j++) {
        int idx = t + j * 256;
        if (idx < 1152) {
            int ch_l = idx / 36;
            float val = pa[idx] + pc[idx] + prim_b[cap * 32 + ch_l];
            v[j] = val; ss += val * val;
        } else v[j] = 0.f;
    }
    for (int off = 32; off; off >>= 1) ss += __shfl_down(ss, off);
    if ((t & 63) == 0) red[t >> 6] = ss;
    __syncthreads();
    float n2 = red[0] + red[1] + red[2] + red[3];
    float f = (n2 / (1.0f + n2)) / (sqrtf(n2) + 1e-10f);
    #pragma unroll
    for (int j = 0; j < 5; j++) {
        int idx = t + j * 256;
        if (idx < 1152) U[(size_t)b * 9216 + idx * 8 + cap] = v[j] * f;
    }
}

// dw (i,c,o,k) -> dwT[(i*8+k)*160 + c*16+o], iteration-invariant
__global__ void k_dwt(const float* __restrict__ dw, float* __restrict__ dwT) {
    __shared__ float lds[1280];
    int i = blockIdx.x, t = threadIdx.x;
    for (int idx = t; idx < 1280; idx += 256) lds[idx] = dw[(size_t)i * 1280 + idx];
    __syncthreads();
    for (int idx = t; idx < 1280; idx += 256) {
        int k = idx / 160, co = idx % 160;
        dwT[(size_t)i * 1280 + idx] = lds[co * 8 + k];
    }
}

__global__ void k_softmax(const float* __restrict__ bij, float* __restrict__ csm) {
    __shared__ float red[4];
    int c = blockIdx.x, t = threadIdx.x;
    float vals[5];
    float mx = -1e30f;
    #pragma unroll
    for (int j = 0; j < 5; j++) {
        int i = t + j * 256;
        vals[j] = (i < 1152) ? bij[i * 10 + c] : -1e30f;
        mx = fmaxf(mx, vals[j]);
    }
    for (int off = 32; off; off >>= 1) mx = fmaxf(mx, __shfl_down(mx, off));
    if ((t & 63) == 0) red[t >> 6] = mx;
    __syncthreads();
    mx = fmaxf(fmaxf(red[0], red[1]), fmaxf(red[2], red[3]));
    __syncthreads();
    float s = 0.f;
    #pragma unroll
    for (int j = 0; j < 5; j++) {
        int i = t + j * 256;
        vals[j] = (i < 1152) ? expf(vals[j] - mx) : 0.f;
        s += vals[j];
    }
    for (int off = 32; off; off >>= 1) s += __shfl_down(s, off);
    if ((t & 63) == 0) red[t >> 6] = s;
    __syncthreads();
    s = red[0] + red[1] + red[2] + red[3];
    float inv = 1.0f / s;
    #pragma unroll
    for (int j = 0; j < 5; j++) {
        int i = t + j * 256;
        if (i < 1152) csm[i * 10 + c] = vals[j] * inv;
    }
}

// s_j partial GEMM with c_ij folded in during staging.
__global__ __launch_bounds__(256) void k_gemm1(const float* __restrict__ U,
                                               const float* __restrict__ dwT,
                                               const float* __restrict__ csm,
                                               float* __restrict__ part,
                                               int uniform) {
    __shared__ float Us[32 * 36];
    __shared__ float Ws[32 * 160];
    __shared__ float cl[360];
    int mb = blockIdx.x, kc = blockIdx.y, t = threadIdx.x;
    int tc = t & 15, tb = t >> 4;
    if (!uniform) {
        for (int idx = t; idx < 360; idx += 256) cl[idx] = csm[kc * 360 + idx];
    }
    __syncthreads();
    const float uscale = 1.0f / 1152.0f;
    float acc[2][10] = {};
    for (int ks = 0; ks < 9; ks++) {
        __syncthreads();
        {
            int bb = t >> 3, k4 = t & 7;
            *(float4*)&Us[bb * 36 + k4 * 4] =
                *(const float4*)&U[(size_t)(mb * 32 + bb) * 9216 + kc * 288 + ks * 32 + k4 * 4];
        }
        for (int idx = t; idx < 1280; idx += 256) {
            int kk = idx / 40, c4 = idx % 40;
            int ik_l = ks * 32 + kk;
            float4 v = *(const float4*)&dwT[(size_t)(kc * 288 + ik_l) * 160 + c4 * 4];
            float sc = uniform ? uscale : cl[(ik_l >> 3) * 10 + (c4 >> 2)];
            v.x *= sc; v.y *= sc; v.z *= sc; v.w *= sc;
            *(float4*)&Ws[kk * 160 + c4 * 4] = v;
        }
        __syncthreads();
        for (int kk = 0; kk < 32; kk++) {
            float a0 = Us[(tb * 2) * 36 + kk], a1 = Us[(tb * 2 + 1) * 36 + kk];
            #pragma unroll
            for (int j = 0; j < 10; j++) {
                float w = Ws[kk * 160 + tc + 16 * j];
                acc[0][j] += a0 * w; acc[1][j] += a1 * w;
            }
        }
    }
    #pragma unroll
    for (int r = 0; r < 2; r++)
        #pragma unroll
        for (int j = 0; j < 10; j++)
            part[(size_t)kc * 40960 + (mb * 32 + tb * 2 + r) * 160 + tc + 16 * j] = acc[r][j];
}

__global__ void k_redsq(const float* __restrict__ part, float* __restrict__ out) {
    __shared__ float sl[160];
    __shared__ float n2s[16];
    int b = blockIdx.x, t = threadIdx.x;
    float s = 0.f;
    if (t < 160) {
        for (int kc = 0; kc < 32; kc++) s += part[(size_t)kc * 40960 + b * 160 + t];
        sl[t] = s;
    }
    __syncthreads();
    if (t < 16) {
        float n2 = 0.f;
        #pragma unroll
        for (int c = 0; c < 10; c++) { float v = sl[c * 16 + t]; n2 += v * v; }
        n2s[t] = n2;
    }
    __syncthreads();
    if (t < 160) {
        float n2 = n2s[t & 15];
        float f = (n2 / (1.0f + n2)) / (sqrtf(n2) + 1e-10f);
        out[(size_t)b * 160 + t] = s * f;
    }
}

// Fused agreement: M2 rows for 4 i's computed in-register, contracted with dw,
// b_ij updated directly (single writer per (i,c)).
__global__ __launch_bounds__(256) void k_g2uv(const float* __restrict__ U,
                                              const float* __restrict__ outv,
                                              const float* __restrict__ dw,
                                              float* __restrict__ bij) {
    __shared__ float Us[32 * 36];
    __shared__ float Os[32 * 160];
    __shared__ float dwl[5120];
    __shared__ float sb[320];
    int blk = blockIdx.x, t = threadIdx.x;
    int tc = t & 15, tm = t >> 4;
    for (int idx = t; idx < 5120; idx += 256)
        dwl[idx] = dw[(size_t)blk * 5120 + idx];
    float acc[2][10] = {};
    for (int bs = 0; bs < 256; bs += 32) {
        __syncthreads();
        {
            int bb = t >> 3, m4 = t & 7;
            *(float4*)&Us[bb * 36 + m4 * 4] =
                *(const float4*)&U[(size_t)(bs + bb) * 9216 + blk * 32 + m4 * 4];
        }
        for (int idx = t; idx < 1280; idx += 256) {
            int bb = idx / 40, c4 = idx % 40;
            *(float4*)&Os[bb * 160 + c4 * 4] =
                *(const float4*)&outv[(size_t)(bs + bb) * 160 + c4 * 4];
        }
        __syncthreads();
        for (int bb = 0; bb < 32; bb++) {
            float a0 = Us[bb * 36 + tm * 2], a1 = Us[bb * 36 + tm * 2 + 1];
            #pragma unroll
            for (int j = 0; j < 10; j++) {
                float w = Os[bb * 160 + tc + 16 * j];
                acc[0][j] += a0 * w; acc[1][j] += a1 * w;
            }
        }
    }
    // contract with dw over o (=tc) per (ik_local, c)
    #pragma unroll
    for (int r = 0; r < 2; r++) {
        int ik_l = tm * 2 + r;
        int i_l = ik_l >> 3, k = ik_l & 7;
        #pragma unroll
        for (int j = 0; j < 10; j++) {
            float v = acc[r][j] * dwl[i_l * 1280 + (j * 16 + tc) * 8 + k];
            v += __shfl_down(v, 8, 16);
            v += __shfl_down(v, 4, 16);
            v += __shfl_down(v, 2, 16);
            v += __shfl_down(v, 1, 16);
            if (tc == 0) sb[ik_l * 10 + j] = v;
        }
    }
    __syncthreads();
    if (t < 40) {
        int i_l = t / 10, c = t % 10;
        float s = 0.f;
        #pragma unroll
        for (int kk = 0; kk < 8; kk++) s += sb[(i_l * 8 + kk) * 10 + c];
        size_t o = (size_t)(blk * 4 + i_l) * 10 + c;
        bij[o] += s * (1.0f / 256.0f);
    }
}

extern "C" void kernel_launch(void* const* d_in, const int* in_sizes, int n_in,
                              void* d_out, int out_size, void* d_ws, size_t ws_size,
                              hipStream_t stream) {
    const float* x      = (const float*)d_in[0];
    const float* conv_w = (const float*)d_in[1];
    const float* conv_b = (const float*)d_in[2];
    const float* prim_w = (const float*)d_in[3];
    const float* prim_b = (const float*)d_in[4];
    const float* dw     = (const float*)d_in[5];

    char* wsb = (char*)d_ws;
    unsigned short* h  = (unsigned short*)(wsb);
    unsigned short* wt = (unsigned short*)(wsb + 52428800);
    float* pp   = (float*)(wsb + 63045632);
    float* U    = (float*)(wsb + 81920000);
    float* dwT  = (float*)(wsb + 91357184);
    float* part = (float*)(wsb + 97255424);
    float* csm  = (float*)(wsb + 102498304);
    float* bij  = (float*)(wsb + 102544384);
    float* outw = (float*)(wsb + 102590464);

    k_makew<<<dim3(32, 8), 256, 0, stream>>>(prim_w, wt);
    k_conv1<<<dim3(256, 8), 256, 0, stream>>>(x, conv_w, conv_b, h);
    k_dwt<<<1152, 256, 0, stream>>>(dw, dwT);
    k_conv2m<<<dim3(72, 4, 2), 256, 0, stream>>>(h, wt, pp);
    k_squash1<<<2048, 256, 0, stream>>>(pp, prim_b, U);
    hipMemsetAsync(bij, 0, 11520 * sizeof(float), stream);

    // iter 0 (b_ij = 0 -> uniform c)
    k_gemm1<<<dim3(8, 32), 256, 0, stream>>>(U, dwT, csm, part, 1);
    k_redsq<<<256, 256, 0, stream>>>(part, outw);
    k_g2uv<<<288, 256, 0, stream>>>(U, outw, dw, bij);
    k_softmax<<<10, 256, 0, stream>>>(bij, csm);
    // iter 1
    k_gemm1<<<dim3(8, 32), 256, 0, stream>>>(U, dwT, csm, part, 0);
    k_redsq<<<256, 256, 0, stream>>>(part, outw);
    k_g2uv<<<288, 256, 0, stream>>>(U, outw, dw, bij);
    k_softmax<<<10, 256, 0, stream>>>(bij, csm);
    // iter 2
    k_gemm1<<<dim3(8, 32), 256, 0, stream>>>(U, dwT, csm, part, 0);
    k_redsq<<<256, 256, 0, stream>>>(part, (float*)d_out);
}

// Round 5
// 508.010 us; speedup vs baseline: 3.5426x; 1.1893x over previous
//
#include <hip/hip_runtime.h>
#include <cstdint>
#include <cstddef>

// ---------------------------------------------------------------------------
// CapsNet forward. Round 5:
//  - conv2m: restore round-3's proven conflict-free LDS geometry (64-short
//    rows, 3-bit XOR chunk swizzle) via two icb-half subregions; still 81
//    staging rounds.
//  - routing GEMMs (gemm1/g2uv): A-panel register cache + b128 B-panel reads
//    from chunk-swizzled transposed LDS (WsT/OsT/UsT), staged lane-linearly
//    from pre-transposed globals dwT2[co][ik], outT[co][b], UT[ik][b].
//  - all-fp32 routing numerics preserved (no new precision risk).
// Workspace (bytes):
//   h    [0, 52428800)           bf16 [b][pix400][ic256]
//   wt   [52428800, 63045632)    bf16 [k81][oc256][ic256]
//   pp   [63045632, 81920000)    f32  2 z-halves of [b][oc][36]
//   U    [81920000, 91357184)    f32  [b][ik]
//   dwT2 [91357184, 97255424)    f32  [co160][ik9216]
//   part [97255424, 102498304)   f32  [kc32][b256][co160]
//   csm  [102498304,102544384)   f32  [i][c]
//   bij  [102544384,102590464)   f32  [i][c]
//   outT [102590464,102754304)   f32  [co160][b256]
//   outw [102754304,102918144)   f32  [b][co160]
//   UT   [102918144,112355328)   f32  [ik9216][b256]
// ---------------------------------------------------------------------------

typedef __attribute__((ext_vector_type(8))) short short8;
typedef __attribute__((ext_vector_type(4))) float f32x4;

#define PHALF 2359296

__device__ __forceinline__ unsigned short f2bf_rn(float x) {
    unsigned u = __float_as_uint(x);
    unsigned r = (u + 0x7fffu + ((u >> 16) & 1u)) >> 16;
    return (unsigned short)r;
}

// prim_w (256 oc, 256 ic, 81) fp32 -> wt[k][oc][ic] bf16
__global__ void k_makew(const float* __restrict__ w2,
                        unsigned short* __restrict__ wt) {
    __shared__ float lw[20736];   // [8 oc][32 ic][81 k]
    int ocg = blockIdx.x, icg = blockIdx.y, t = threadIdx.x;
    for (int idx = t; idx < 20736; idx += 256) {
        int row = idx / 81, k = idx % 81;
        int oc_l = row >> 5, ic_l = row & 31;
        lw[idx] = w2[((size_t)(ocg * 8 + oc_l) * 256 + icg * 32 + ic_l) * 81 + k];
    }
    __syncthreads();
    for (int idx = t; idx < 2592; idx += 256) {   // 81 k * 8 oc * 4 slots
        int k = idx >> 5;
        int r = idx & 31;
        int oc_l = r >> 2, sl = r & 3;
        unsigned short hi8[8];
        #pragma unroll
        for (int j = 0; j < 8; j++)
            hi8[j] = f2bf_rn(lw[(oc_l * 32 + sl * 8 + j) * 81 + k]);
        size_t o = ((size_t)(k * 256 + ocg * 8 + oc_l)) * 256 + icg * 32 + sl * 8;
        *(uint4*)&wt[o] = *(uint4*)hi8;
    }
}

__global__ void k_conv1(const float* __restrict__ x, const float* __restrict__ cw,
                        const float* __restrict__ cb,
                        unsigned short* __restrict__ h) {
    // grid (256 b, 8 ocg), block 256
    __shared__ float img[784];
    __shared__ float wsm[32 * 81];
    int b = blockIdx.x, ocg = blockIdx.y, t = threadIdx.x;
    for (int idx = t; idx < 784; idx += 256) img[idx] = x[b * 784 + idx];
    for (int idx = t; idx < 2592; idx += 256) wsm[idx] = cw[ocg * 2592 + idx];
    __syncthreads();
    int oc_l = t & 31, g = t >> 5;
    int oc = ocg * 32 + oc_l;
    float bias = cb[oc];
    const float* wp = &wsm[oc_l * 81];
    for (int q = g; q < 100; q += 8) {
        int py = q / 5, qx = (q % 5) * 4;
        float a0 = bias, a1 = bias, a2 = bias, a3 = bias;
        #pragma unroll
        for (int ky = 0; ky < 9; ky++) {
            const float* ir = &img[(py + ky) * 28 + qx];
            float r[12];
            #pragma unroll
            for (int j = 0; j < 12; j++) r[j] = ir[j];
            #pragma unroll
            for (int kx = 0; kx < 9; kx++) {
                float w = wp[ky * 9 + kx];
                a0 += r[kx] * w; a1 += r[kx + 1] * w;
                a2 += r[kx + 2] * w; a3 += r[kx + 3] * w;
            }
        }
        float v[4] = { fmaxf(a0, 0.f), fmaxf(a1, 0.f), fmaxf(a2, 0.f), fmaxf(a3, 0.f) };
        size_t base = ((size_t)b * 400 + py * 20 + qx) * 256 + oc;
        #pragma unroll
        for (int j = 0; j < 4; j++)
            h[base + (size_t)j * 256] = f2bf_rn(v[j]);
    }
}

// Implicit-GEMM bf16 MFMA conv2. grid (72 mb, 4 nb, 2 z), block 256 (4 waves).
// Tile: 128 pix x 64 oc; 81 rounds, each staging 128 ic as TWO 64-ic half
// subregions with 64-short rows (round-3 verified conflict-free geometry).
__global__ __launch_bounds__(256) void k_conv2m(
    const unsigned short* __restrict__ h,
    const unsigned short* __restrict__ wt,
    float* __restrict__ pp)
{
    // A: half hh at hh*8192, rows pix*64 | W: half hh at 16384 + hh*4096, rows oc*64
    __shared__ unsigned short smem[24576];   // 49152 B
    const int t = threadIdx.x;
    const int w = t >> 6, l = t & 63;
    const int mb = blockIdx.x, nb = blockIdx.y, z = blockIdx.z;

    // staging roles: w0 A-half0, w1 A-half1, w2 W-half0, w3 W-half1
    const unsigned short* src;
    int nld, sbase;
    unsigned rowbase[16];
    if (w < 2) {
        src = h; nld = 16; sbase = w * 8192;
        #pragma unroll
        for (int ld = 0; ld < 16; ld++) {
            int row = ld * 8 + (l >> 3);           // pixel local 0..127
            int c = l & 7;
            int g = c ^ (row & 7);
            int P = mb * 128 + row;
            int b = P / 36, o = P % 36;
            int oy = o / 6, ox = o % 6;
            rowbase[ld] = (unsigned)((b * 400 + oy * 40 + ox * 2) * 256 + z * 128 + w * 64 + g * 8);
        }
    } else {
        int hh = w - 2;
        src = wt; nld = 8; sbase = 16384 + hh * 4096;
        #pragma unroll
        for (int ld = 0; ld < 8; ld++) {
            int oc = ld * 8 + (l >> 3);            // 0..63
            int c = l & 7;
            int g = c ^ (oc & 7);
            rowbase[ld] = (unsigned)((nb * 64 + oc) * 256 + z * 128 + hh * 64 + g * 8);
        }
    }

    // compute setup: waves 2x2, wave tile 64 pix x 32 oc
    const int wm = w & 1, wn = w >> 1;
    const int lane16 = l & 15, q = l >> 4;

    f32x4 acc[4][2] = {};

    for (int ky = 0; ky < 9; ky++) {
        for (int kx = 0; kx < 9; kx++) {
            const unsigned kofs = (w < 2) ? (unsigned)((ky * 20 + kx) * 256)
                                          : (unsigned)((ky * 9 + kx) * 65536);
            __syncthreads();
            for (int ld = 0; ld < nld; ld++) {
                __builtin_amdgcn_global_load_lds(
                    (const __attribute__((address_space(1))) unsigned int*)(const void*)(src + rowbase[ld] + kofs),
                    (__attribute__((address_space(3))) unsigned int*)(void*)(smem + sbase + ld * 512),
                    16, 0, 0);
            }
            __syncthreads();
            #pragma unroll
            for (int hh = 0; hh < 2; hh++) {
                #pragma unroll
                for (int ic2 = 0; ic2 < 2; ic2++) {
                    short8 a[4], b[2];
                    #pragma unroll
                    for (int mt = 0; mt < 4; mt++) {
                        int pixL = wm * 64 + mt * 16 + lane16;
                        int ps = (ic2 * 4 + q) ^ (pixL & 7);
                        a[mt] = *(const short8*)(smem + hh * 8192 + pixL * 64 + ps * 8);
                    }
                    #pragma unroll
                    for (int nt = 0; nt < 2; nt++) {
                        int ocL = wn * 32 + nt * 16 + lane16;
                        int ps = (ic2 * 4 + q) ^ (ocL & 7);
                        b[nt] = *(const short8*)(smem + 16384 + hh * 4096 + ocL * 64 + ps * 8);
                    }
                    #pragma unroll
                    for (int mt = 0; mt < 4; mt++)
                        #pragma unroll
                        for (int nt = 0; nt < 2; nt++)
                            acc[mt][nt] = __builtin_amdgcn_mfma_f32_16x16x32_bf16(a[mt], b[nt], acc[mt][nt], 0, 0, 0);
                }
            }
        }
    }

    // epilogue: D row = q*4+reg (pixel), col = lane16 (oc)
    float* pout = pp + (size_t)z * PHALF;
    #pragma unroll
    for (int mt = 0; mt < 4; mt++) {
        int pixG = mb * 128 + wm * 64 + mt * 16 + q * 4;
        int b = pixG / 36, p36 = pixG % 36;
        #pragma unroll
        for (int nt = 0; nt < 2; nt++) {
            int oc = nb * 64 + wn * 32 + nt * 16 + lane16;
            f32x4 v = acc[mt][nt];
            *(f32x4*)&pp[0] ;  // no-op guard against compiler reorder (removed below)
            *(f32x4*)&pout[((size_t)(b * 256 + oc)) * 36 + p36] = v;
        }
    }
}

__global__ void k_squash1(const float* __restrict__ pp, const float* __restrict__ prim_b,
                          float* __restrict__ U) {
    // grid 2048 (b*8+cap), block 256
    __shared__ float red[4];
    int b = blockIdx.x >> 3, cap = blockIdx.x & 7;
    int t = threadIdx.x;
    const float* pa = pp + ((size_t)b * 256 + cap * 32) * 36;
    const float* pc = pa + PHALF;
    float v[5];
    float ss = 0.f;
    #pragma unroll
    for (int j = 0; j < 5; j++) {
        int idx = t + j * 256;
        if (idx < 1152) {
            int ch_l = idx / 36;
            float val = pa[idx] + pc[idx] + prim_b[cap * 32 + ch_l];
            v[j] = val; ss += val * val;
        } else v[j] = 0.f;
    }
    for (int off = 32; off; off >>= 1) ss += __shfl_down(ss, off);
    if ((t & 63) == 0) red[t >> 6] = ss;
    __syncthreads();
    float n2 = red[0] + red[1] + red[2] + red[3];
    float f = (n2 / (1.0f + n2)) / (sqrtf(n2) + 1e-10f);
    #pragma unroll
    for (int j = 0; j < 5; j++) {
        int idx = t + j * 256;
        if (idx < 1152) U[(size_t)b * 9216 + idx * 8 + cap] = v[j] * f;
    }
}

// dw (i,c,o,k) -> dwT2[co160][ik9216]
__global__ void k_dwt2(const float* __restrict__ dw, float* __restrict__ dwT2) {
    int co = blockIdx.x, t = threadIdx.x;
    int c = co >> 4, o = co & 15;
    const float* base = dw + c * 128 + o * 8;
    float* out = dwT2 + (size_t)co * 9216;
    for (int idx = t; idx < 9216; idx += 256) {
        int i = idx >> 3, k = idx & 7;
        out[idx] = base[(size_t)i * 1280 + k];
    }
}

// U[b][ik] -> UT[ik][b], 64x64 tiles
__global__ void k_ut(const float* __restrict__ U, float* __restrict__ UT) {
    __shared__ float tl[64][65];
    int ikb = blockIdx.x, bb = blockIdx.y, t = threadIdx.x;
    for (int idx = t; idx < 1024; idx += 256) {
        int row = idx >> 4, c4 = idx & 15;
        float4 v = *(const float4*)&U[(size_t)(bb * 64 + row) * 9216 + ikb * 64 + c4 * 4];
        tl[c4 * 4 + 0][row] = v.x;
        tl[c4 * 4 + 1][row] = v.y;
        tl[c4 * 4 + 2][row] = v.z;
        tl[c4 * 4 + 3][row] = v.w;
    }
    __syncthreads();
    for (int idx = t; idx < 1024; idx += 256) {
        int row = idx >> 4, c4 = idx & 15;
        float4 v = make_float4(tl[row][c4 * 4 + 0], tl[row][c4 * 4 + 1],
                               tl[row][c4 * 4 + 2], tl[row][c4 * 4 + 3]);
        *(float4*)&UT[(size_t)(ikb * 64 + row) * 256 + bb * 64 + c4 * 4] = v;
    }
}

__global__ void k_softmax(const float* __restrict__ bij, float* __restrict__ csm) {
    __shared__ float red[4];
    int c = blockIdx.x, t = threadIdx.x;
    float vals[5];
    float mx = -1e30f;
    #pragma unroll
    for (int j = 0; j < 5; j++) {
        int i = t + j * 256;
        vals[j] = (i < 1152) ? bij[i * 10 + c] : -1e30f;
        mx = fmaxf(mx, vals[j]);
    }
    for (int off = 32; off; off >>= 1) mx = fmaxf(mx, __shfl_down(mx, off));
    if ((t & 63) == 0) red[t >> 6] = mx;
    __syncthreads();
    mx = fmaxf(fmaxf(red[0], red[1]), fmaxf(red[2], red[3]));
    __syncthreads();
    float s = 0.f;
    #pragma unroll
    for (int j = 0; j < 5; j++) {
        int i = t + j * 256;
        vals[j] = (i < 1152) ? expf(vals[j] - mx) : 0.f;
        s += vals[j];
    }
    for (int off = 32; off; off >>= 1) s += __shfl_down(s, off);
    if ((t & 63) == 0) red[t >> 6] = s;
    __syncthreads();
    s = red[0] + red[1] + red[2] + red[3];
    float inv = 1.0f / s;
    #pragma unroll
    for (int j = 0; j < 5; j++) {
        int i = t + j * 256;
        if (i < 1152) csm[i * 10 + c] = vals[j] * inv;
    }
}

// s_j partial GEMM. A-panel register cache + b128 swizzled WsT reads.
// grid (8 mb, 32 kc), block 256. part[kc][row][160].
__global__ __launch_bounds__(256) void k_gemm1(const float* __restrict__ U,
                                               const float* __restrict__ dwT2,
                                               const float* __restrict__ csm,
                                               float* __restrict__ part,
                                               int uniform) {
    __shared__ float Us[32 * 36];     // [row][kk 32 +pad]
    __shared__ float WsT[5120];       // [co160][chunk8 swizzled][4]
    __shared__ float cl[360];
    int mb = blockIdx.x, kc = blockIdx.y, t = threadIdx.x;
    int tc = t & 15, tb = t >> 4;
    if (!uniform)
        for (int idx = t; idx < 360; idx += 256) cl[idx] = csm[kc * 360 + idx];
    const float uscale = 1.0f / 1152.0f;
    float acc[2][10] = {};
    for (int ks = 0; ks < 9; ks++) {
        __syncthreads();
        {   // stage Us: 32 rows x 32 kk
            int bb = t >> 3, k4 = t & 7;
            *(float4*)&Us[bb * 36 + k4 * 4] =
                *(const float4*)&U[(size_t)(mb * 32 + bb) * 9216 + kc * 288 + ks * 32 + k4 * 4];
        }
        // stage WsT lane-linear with chunk swizzle; fold c_ij
        #pragma unroll
        for (int pass = 0; pass < 5; pass++) {
            int s = t + pass * 256;
            int co = s >> 3, p = s & 7;
            int kq = p ^ (co & 7);
            int ikl = ks * 32 + kq * 4;
            float4 v = *(const float4*)&dwT2[(size_t)co * 9216 + kc * 288 + ikl];
            float sc = uniform ? uscale : cl[(ikl >> 3) * 10 + (co >> 4)];
            v.x *= sc; v.y *= sc; v.z *= sc; v.w *= sc;
            *(float4*)&WsT[s * 4] = v;
        }
        __syncthreads();
        // A-panel into registers: 2 rows x 32 kk
        float a0[32], a1[32];
        #pragma unroll
        for (int kq = 0; kq < 8; kq++) {
            float4 v0 = *(const float4*)&Us[(tb * 2) * 36 + kq * 4];
            float4 v1 = *(const float4*)&Us[(tb * 2 + 1) * 36 + kq * 4];
            a0[kq * 4 + 0] = v0.x; a0[kq * 4 + 1] = v0.y; a0[kq * 4 + 2] = v0.z; a0[kq * 4 + 3] = v0.w;
            a1[kq * 4 + 0] = v1.x; a1[kq * 4 + 1] = v1.y; a1[kq * 4 + 2] = v1.z; a1[kq * 4 + 3] = v1.w;
        }
        #pragma unroll
        for (int j = 0; j < 10; j++) {
            int co = tc + 16 * j;
            int cx = co & 7, cbase = co * 32;
            #pragma unroll
            for (int kq = 0; kq < 8; kq++) {
                float4 wv = *(const float4*)&WsT[cbase + ((kq ^ cx) << 2)];
                acc[0][j] += a0[kq * 4 + 0] * wv.x; acc[0][j] += a0[kq * 4 + 1] * wv.y;
                acc[0][j] += a0[kq * 4 + 2] * wv.z; acc[0][j] += a0[kq * 4 + 3] * wv.w;
                acc[1][j] += a1[kq * 4 + 0] * wv.x; acc[1][j] += a1[kq * 4 + 1] * wv.y;
                acc[1][j] += a1[kq * 4 + 2] * wv.z; acc[1][j] += a1[kq * 4 + 3] * wv.w;
            }
        }
    }
    #pragma unroll
    for (int r = 0; r < 2; r++)
        #pragma unroll
        for (int j = 0; j < 10; j++)
            part[(size_t)kc * 40960 + (mb * 32 + tb * 2 + r) * 160 + tc + 16 * j] = acc[r][j];
}

__global__ void k_redsq(const float* __restrict__ part, float* __restrict__ out,
                        float* __restrict__ outT, int writeT) {
    __shared__ float sl[160];
    __shared__ float n2s[16];
    int b = blockIdx.x, t = threadIdx.x;
    float s = 0.f;
    if (t < 160) {
        for (int kc = 0; kc < 32; kc++) s += part[(size_t)kc * 40960 + b * 160 + t];
        sl[t] = s;
    }
    __syncthreads();
    if (t < 16) {
        float n2 = 0.f;
        #pragma unroll
        for (int c = 0; c < 10; c++) { float v = sl[c * 16 + t]; n2 += v * v; }
        n2s[t] = n2;
    }
    __syncthreads();
    if (t < 160) {
        float n2 = n2s[t & 15];
        float f = (n2 / (1.0f + n2)) / (sqrtf(n2) + 1e-10f);
        float r = s * f;
        out[(size_t)b * 160 + t] = r;
        if (writeT) outT[(size_t)t * 256 + b] = r;
    }
}

// Fused agreement via UT/outT: M2 rows in-register (b128 swizzled LDS reads),
// contracted with dw, bij updated. grid 288 (4 i's each), block 256.
__global__ __launch_bounds__(256) void k_g2uv(const float* __restrict__ UT,
                                              const float* __restrict__ outTg,
                                              const float* __restrict__ dw,
                                              float* __restrict__ bij) {
    __shared__ float UsT[1024];    // [m32][chunk8 swizzled][4]
    __shared__ float OsT[5120];    // [co160][chunk8 swizzled][4]
    __shared__ float dwl[5120];
    __shared__ float sb[320];
    int blk = blockIdx.x, t = threadIdx.x;
    int tc = t & 15, tm = t >> 4;
    for (int idx = t; idx < 5120; idx += 256)
        dwl[idx] = dw[(size_t)blk * 5120 + idx];
    float acc[2][10] = {};
    for (int bs = 0; bs < 256; bs += 32) {
        __syncthreads();
        {   // stage UsT lane-linear, swizzled
            int m = t >> 3, p = t & 7;
            int kq = p ^ (m & 7);
            *(float4*)&UsT[t * 4] =
                *(const float4*)&UT[(size_t)(blk * 32 + m) * 256 + bs + kq * 4];
        }
        #pragma unroll
        for (int pass = 0; pass < 5; pass++) {
            int s = t + pass * 256;
            int co = s >> 3, p = s & 7;
            int kq = p ^ (co & 7);
            *(float4*)&OsT[s * 4] =
                *(const float4*)&outTg[(size_t)co * 256 + bs + kq * 4];
        }
        __syncthreads();
        float a0[32], a1[32];
        int m0 = tm * 2, m1 = tm * 2 + 1;
        #pragma unroll
        for (int kq = 0; kq < 8; kq++) {
            float4 v0 = *(const float4*)&UsT[m0 * 32 + ((kq ^ (m0 & 7)) << 2)];
            float4 v1 = *(const float4*)&UsT[m1 * 32 + ((kq ^ (m1 & 7)) << 2)];
            a0[kq * 4 + 0] = v0.x; a0[kq * 4 + 1] = v0.y; a0[kq * 4 + 2] = v0.z; a0[kq * 4 + 3] = v0.w;
            a1[kq * 4 + 0] = v1.x; a1[kq * 4 + 1] = v1.y; a1[kq * 4 + 2] = v1.z; a1[kq * 4 + 3] = v1.w;
        }
        #pragma unroll
        for (int j = 0; j < 10; j++) {
            int co = tc + 16 * j;
            int cx = co & 7, cbase = co * 32;
            #pragma unroll
            for (int kq = 0; kq < 8; kq++) {
                float4 wv = *(const float4*)&OsT[cbase + ((kq ^ cx) << 2)];
                acc[0][j] += a0[kq * 4 + 0] * wv.x; acc[0][j] += a0[kq * 4 + 1] * wv.y;
                acc[0][j] += a0[kq * 4 + 2] * wv.z; acc[0][j] += a0[kq * 4 + 3] * wv.w;
                acc[1][j] += a1[kq * 4 + 0] * wv.x; acc[1][j] += a1[kq * 4 + 1] * wv.y;
                acc[1][j] += a1[kq * 4 + 2] * wv.z; acc[1][j] += a1[kq * 4 + 3] * wv.w;
            }
        }
    }
    // contract with dw over o (=tc) per (ik_local, c)
    #pragma unroll
    for (int r = 0; r < 2; r++) {
        int ik_l = tm * 2 + r;
        int i_l = ik_l >> 3, k = ik_l & 7;
        #pragma unroll
        for (int j = 0; j < 10; j++) {
            float v = acc[r][j] * dwl[i_l * 1280 + (j * 16 + tc) * 8 + k];
            v += __shfl_down(v, 8, 16);
            v += __shfl_down(v, 4, 16);
            v += __shfl_down(v, 2, 16);
            v += __shfl_down(v, 1, 16);
            if (tc == 0) sb[ik_l * 10 + j] = v;
        }
    }
    __syncthreads();
    if (t < 40) {
        int i_l = t / 10, c = t % 10;
        float s = 0.f;
        #pragma unroll
        for (int kk = 0; kk < 8; kk++) s += sb[(i_l * 8 + kk) * 10 + c];
        size_t o = (size_t)(blk * 4 + i_l) * 10 + c;
        bij[o] += s * (1.0f / 256.0f);
    }
}

extern "C" void kernel_launch(void* const* d_in, const int* in_sizes, int n_in,
                              void* d_out, int out_size, void* d_ws, size_t ws_size,
                              hipStream_t stream) {
    const float* x      = (const float*)d_in[0];
    const float* conv_w = (const float*)d_in[1];
    const float* conv_b = (const float*)d_in[2];
    const float* prim_w = (const float*)d_in[3];
    const float* prim_b = (const float*)d_in[4];
    const float* dw     = (const float*)d_in[5];

    char* wsb = (char*)d_ws;
    unsigned short* h  = (unsigned short*)(wsb);
    unsigned short* wt = (unsigned short*)(wsb + 52428800);
    float* pp   = (float*)(wsb + 63045632);
    float* U    = (float*)(wsb + 81920000);
    float* dwT2 = (float*)(wsb + 91357184);
    float* part = (float*)(wsb + 97255424);
    float* csm  = (float*)(wsb + 102498304);
    float* bij  = (float*)(wsb + 102544384);
    float* outT = (float*)(wsb + 102590464);
    float* outw = (float*)(wsb + 102754304);
    float* UT   = (float*)(wsb + 102918144);

    k_makew<<<dim3(32, 8), 256, 0, stream>>>(prim_w, wt);
    k_conv1<<<dim3(256, 8), 256, 0, stream>>>(x, conv_w, conv_b, h);
    k_dwt2<<<160, 256, 0, stream>>>(dw, dwT2);
    k_conv2m<<<dim3(72, 4, 2), 256, 0, stream>>>(h, wt, pp);
    k_squash1<<<2048, 256, 0, stream>>>(pp, prim_b, U);
    k_ut<<<dim3(144, 4), 256, 0, stream>>>(U, UT);
    hipMemsetAsync(bij, 0, 11520 * sizeof(float), stream);

    // iter 0 (b_ij = 0 -> uniform c)
    k_gemm1<<<dim3(8, 32), 256, 0, stream>>>(U, dwT2, csm, part, 1);
    k_redsq<<<256, 256, 0, stream>>>(part, outw, outT, 1);
    k_g2uv<<<288, 256, 0, stream>>>(UT, outT, dw, bij);
    k_softmax<<<10, 256, 0, stream>>>(bij, csm);
    // iter 1
    k_gemm1<<<dim3(8, 32), 256, 0, stream>>>(U, dwT2, csm, part, 0);
    k_redsq<<<256, 256, 0, stream>>>(part, outw, outT, 1);
    k_g2uv<<<288, 256, 0, stream>>>(UT, outT, dw, bij);
    k_softmax<<<10, 256, 0, stream>>>(bij, csm);
    // iter 2
    k_gemm1<<<dim3(8, 32), 256, 0, stream>>>(U, dwT2, csm, part, 0);
    k_redsq<<<256, 256, 0, stream>>>(part, (float*)d_out, outT, 0);
}